// Round 1
// baseline (216.916 us; speedup 1.0000x reference)
//
#include <hip/hip_runtime.h>

#define NATOM   4096
#define NG4     (NATOM / 4)       // 1024 float4 groups per row
#define NBOND   6144
#define NANGLE  8192
#define NUB     4096
#define NDIH    12288
#define NIMP    2048

#define NB_BLOCKS   2048          // block b -> rows b and NATOM-1-b (merged stream)
#define BOND_ITEMS  (NBOND + NANGLE + NUB + NDIH + NIMP)   // 32768
#define ITEMS_PER_BLOCK (BOND_ITEMS / NB_BLOCKS)            // 16, exact
#define TOTAL_SLOTS NB_BLOCKS                               // 2048 doubles in d_ws

#define DEG2RAD 0.017453292519943295f

// ---- block reduction (sum of doubles), result valid on thread 0 ----
static __device__ __forceinline__ double block_reduce(double v, double* sm) {
    #pragma unroll
    for (int off = 32; off > 0; off >>= 1) v += __shfl_down(v, off, 64);
    const int lane = threadIdx.x & 63, wid = threadIdx.x >> 6;
    __syncthreads();                 // safe LDS reuse across successive calls
    if (lane == 0) sm[wid] = v;
    __syncthreads();
    double r = 0.0;
    if (threadIdx.x == 0) {
        const int nw = blockDim.x >> 6;
        for (int w = 0; w < nw; ++w) r += sm[w];
    }
    return r;
}

// one pair's vdW + electrostatic contribution (f32), predicated
static __device__ __forceinline__ float pair_term(
    float xi0, float xi1, float xi2,
    float xj0, float xj1, float xj2,
    float e, float r, float q, bool valid)
{
    const float dx = xi0 - xj0, dy = xi1 - xj1, dz = xi2 - xj2;
    float d2 = fmaf(dx, dx, fmaf(dy, dy, dz * dz));
    d2 = fmaxf(d2, 1e-12f);
    float inv = rsqrtf(d2);                       // ~1-2 ulp
    const float t = inv * inv;
    inv = inv * fmaf(-0.5f * d2, t, 1.5f);        // one Newton step -> ~0.5 ulp
    const float rod = r * inv;
    const float r2 = rod * rod;
    const float r6 = r2 * r2 * r2;
    const float v = fmaf(e * r6, r6 - 2.0f, q * inv);
    return valid ? v : 0.0f;
}

// process one float4-group of row `i` (coords of i given), f32 partial
static __device__ __forceinline__ float group_term(
    int i, float xi0, float xi1, float xi2, int g,
    float4 e, float4 r, float4 q, float4 xa, float4 xb, float4 xc)
{
    const int j0 = 4 * g;
    float s;
    s  = pair_term(xi0,xi1,xi2, xa.x,xa.y,xa.z, e.x,r.x,q.x, j0+0 > i);
    s += pair_term(xi0,xi1,xi2, xa.w,xb.x,xb.y, e.y,r.y,q.y, j0+1 > i);
    s += pair_term(xi0,xi1,xi2, xb.z,xb.w,xc.x, e.z,r.z,q.z, j0+2 > i);
    s += pair_term(xi0,xi1,xi2, xc.y,xc.z,xc.w, e.w,r.w,q.w, j0+3 > i);
    return s;
}

// ---------------- bonded terms ----------------
static __device__ __forceinline__ float torsion(const float* __restrict__ x,
                                                int i0, int i1, int i2, int i3) {
    const float ax = x[3*i1] - x[3*i0], ay = x[3*i1+1] - x[3*i0+1], az = x[3*i1+2] - x[3*i0+2];
    const float bx = x[3*i2] - x[3*i1], by = x[3*i2+1] - x[3*i1+1], bz = x[3*i2+2] - x[3*i1+2];
    const float cx = x[3*i3] - x[3*i2], cy = x[3*i3+1] - x[3*i2+1], cz = x[3*i3+2] - x[3*i2+2];
    const float n1x = ay*bz - az*by, n1y = az*bx - ax*bz, n1z = ax*by - ay*bx;
    const float n2x = by*cz - bz*cy, n2y = bz*cx - bx*cz, n2z = bx*cy - by*cx;
    const float dt  = n1x*n2x + n1y*n2y + n1z*n2z;
    const float nn1 = sqrtf(n1x*n1x + n1y*n1y + n1z*n1z);
    const float nn2 = sqrtf(n2x*n2x + n2y*n2y + n2z*n2z);
    float c = dt / (nn1 * nn2);
    c = fminf(fmaxf(c, -0.9999f), 0.9999f);
    const float ang = acosf(c);
    const float sx = n1y*n2z - n1z*n2y, sy = n1z*n2x - n1x*n2z, sz = n1x*n2y - n1y*n2x;
    const float s = sx*bx + sy*by + sz*bz;
    const float sg = (s > 0.0f) ? 1.0f : ((s < 0.0f) ? -1.0f : 0.0f);
    return ang * sg;
}

// bonded item t in [0, BOND_ITEMS): returns its energy contribution (f32)
static __device__ __forceinline__ float bonded_item(
    const float* __restrict__ x, int t,
    const float* __restrict__ kb, const float* __restrict__ b0,
    const float* __restrict__ kt, const float* __restrict__ t0,
    const float* __restrict__ ku, const float* __restrict__ s0,
    const float* __restrict__ kd, const float* __restrict__ nd, const float* __restrict__ d0,
    const float* __restrict__ kp, const float* __restrict__ p0,
    const int* __restrict__ bond, const int* __restrict__ angle,
    const int* __restrict__ ub,   const int* __restrict__ dih,
    const int* __restrict__ imp)
{
    if (t < NBOND) {
        const int m = t;
        const int i = bond[2*m], j = bond[2*m+1];
        const float dx = x[3*i]-x[3*j], dy = x[3*i+1]-x[3*j+1], dz = x[3*i+2]-x[3*j+2];
        const float dis = sqrtf(dx*dx + dy*dy + dz*dz);
        const float d = dis - b0[m];
        return kb[m] * d * d;
    } else if (t < NBOND + NANGLE) {
        const int m = t - NBOND;
        const int i = angle[3*m], j = angle[3*m+1], k = angle[3*m+2];
        const float bax = x[3*i]-x[3*j], bay = x[3*i+1]-x[3*j+1], baz = x[3*i+2]-x[3*j+2];
        const float bcx = x[3*k]-x[3*j], bcy = x[3*k+1]-x[3*j+1], bcz = x[3*k+2]-x[3*j+2];
        const float dt  = bax*bcx + bay*bcy + baz*bcz;
        const float na  = sqrtf(bax*bax + bay*bay + baz*baz);
        const float nb  = sqrtf(bcx*bcx + bcy*bcy + bcz*bcz);
        float c = dt / (na * nb);
        c = fminf(fmaxf(c, -0.9999f), 0.9999f);
        const float theta = acosf(c);
        const float d = theta - t0[m] * DEG2RAD;
        return kt[m] * d * d;
    } else if (t < NBOND + NANGLE + NUB) {
        const int m = t - NBOND - NANGLE;
        const int i = ub[2*m], j = ub[2*m+1];
        const float dx = x[3*i]-x[3*j], dy = x[3*i+1]-x[3*j+1], dz = x[3*i+2]-x[3*j+2];
        const float dis = sqrtf(dx*dx + dy*dy + dz*dz);
        const float d = dis - s0[m];
        return ku[m] * d * d;
    } else if (t < NBOND + NANGLE + NUB + NDIH) {
        const int m = t - NBOND - NANGLE - NUB;
        const float delta = torsion(x, dih[4*m], dih[4*m+1], dih[4*m+2], dih[4*m+3]);
        return kd[m] * (1.0f + cosf(nd[m] * delta - d0[m] * DEG2RAD));
    } else {
        const int m = t - NBOND - NANGLE - NUB - NDIH;
        const float psi = torsion(x, imp[4*m], imp[4*m+1], imp[4*m+2], imp[4*m+3]);
        const float d = psi - p0[m] * DEG2RAD;
        return kp[m] * d * d;
    }
}

// ---------------- fused kernel: 2048 uniform blocks ----------------
// Block b: nonbonded rows {b, 4095-b} merged into one balanced 1024/1025-slot
// stream (no predicated over-compute), + 16 bonded items, + central (block 0).
__global__ __launch_bounds__(256) void ff_kernel(
    const float4* __restrict__ xv,
    const float4* __restrict__ eps,
    const float4* __restrict__ rmin,
    const float4* __restrict__ kqq,
    const float* __restrict__ kb, const float* __restrict__ b0,
    const float* __restrict__ kt, const float* __restrict__ t0,
    const float* __restrict__ ku, const float* __restrict__ s0,
    const float* __restrict__ kd, const float* __restrict__ nd, const float* __restrict__ d0,
    const float* __restrict__ kp, const float* __restrict__ p0,
    const int* __restrict__ bond, const int* __restrict__ angle,
    const int* __restrict__ ub,   const int* __restrict__ dih,
    const int* __restrict__ imp,  const int* __restrict__ central,
    double* __restrict__ ws)
{
    __shared__ double sm[4];
    const float* __restrict__ x = (const float*)xv;
    const int b = (int)blockIdx.x;
    const int t = (int)threadIdx.x;

    // ---------------- nonbonded (merged rows) ----------------
    const int i0 = b, i1 = NATOM - 1 - b;
    const int g00 = (i0 + 1) >> 2;       // first group of row i0
    const int g01 = (i1 + 1) >> 2;       // first group of row i1
    const int c0  = NG4 - g00;           // valid slots for row i0
    const int c1  = NG4 - g01;           // valid slots for row i1
    const int S   = c0 + c1;             // 1024 or 1025

    const float a0x = x[3*i0], a0y = x[3*i0+1], a0z = x[3*i0+2];
    const float a1x = x[3*i1], a1y = x[3*i1+1], a1z = x[3*i1+2];

    // slot s in [0,1024): s < c0 -> (row i0, group g00+s); else (row i1, group g01+s-c0)
    int   gs[4], is[4], idx[4];
    float xs0[4], xs1[4], xs2[4];
    #pragma unroll
    for (int u = 0; u < 4; ++u) {
        const int s   = t + (u << 8);
        const bool in0 = s < c0;
        const int g   = in0 ? (g00 + s) : (g01 + (s - c0));
        gs[u]  = g;
        is[u]  = in0 ? i0 : i1;
        xs0[u] = in0 ? a0x : a1x;
        xs1[u] = in0 ? a0y : a1y;
        xs2[u] = in0 ? a0z : a1z;
        idx[u] = (in0 ? i0 : i1) * NG4 + g;      // < 2^22, 32-bit safe
    }

    // phase A: 12 independent coalesced matrix loads back-to-back
    float4 le[4], lr[4], lq[4];
    #pragma unroll
    for (int u = 0; u < 4; ++u) le[u] = eps [idx[u]];
    #pragma unroll
    for (int u = 0; u < 4; ++u) lr[u] = rmin[idx[u]];
    #pragma unroll
    for (int u = 0; u < 4; ++u) lq[u] = kqq [idx[u]];

    // phase B: coords (L1/L2-hot) + math; all 1024 base slots are valid
    double acc = 0.0;
    #pragma unroll
    for (int u = 0; u < 4; ++u) {
        const int g3 = 3 * gs[u];
        const float4 xa = xv[g3], xb = xv[g3+1], xc = xv[g3+2];
        acc += (double)group_term(is[u], xs0[u], xs1[u], xs2[u], gs[u],
                                  le[u], lr[u], lq[u], xa, xb, xc);
    }

    // rare 1025th slot (S == 1025 for b%4 in {1,2}): one group on row i1
    if (S > 1024) {                       // uniform per block
        if (t == 0) {
            const int g  = g01 + (1024 - c0);
            const int id = i1 * NG4 + g;
            const float4 e = eps[id], r = rmin[id], q = kqq[id];
            const int g3 = 3 * g;
            const float4 xa = xv[g3], xb = xv[g3+1], xc = xv[g3+2];
            acc += (double)group_term(i1, a1x, a1y, a1z, g, e, r, q, xa, xb, xc);
        }
    }

    // ---------------- bonded: exactly 16 items per block ----------------
    if (t < ITEMS_PER_BLOCK) {
        const int item = b * ITEMS_PER_BLOCK + t;
        acc += (double)bonded_item(x, item, kb, b0, kt, t0, ku, s0,
                                   kd, nd, d0, kp, p0, bond, angle, ub, dih, imp);
    }

    // ---------------- central term: block 0 only ----------------
    double cext = 0.0;
    if (b == 0) {
        if (*central != 0) {              // uniform per block
            double sx = 0.0, sy = 0.0, sz = 0.0, s2 = 0.0;
            for (int i = t; i < NATOM; i += 256) {
                const float px = x[3*i], py = x[3*i+1], pz = x[3*i+2];
                sx += px; sy += py; sz += pz;
                s2 += (double)px*px + (double)py*py + (double)pz*pz;
            }
            const double rx = block_reduce(sx, sm);
            const double ry = block_reduce(sy, sm);
            const double rz = block_reduce(sz, sm);
            const double r2 = block_reduce(s2, sm);
            if (t == 0)
                cext = 0.1 * (r2 - (rx*rx + ry*ry + rz*rz) / (double)NATOM);
        }
    }

    const double tot = block_reduce(acc, sm);
    if (t == 0) ws[b] = tot + cext;
}

// ---------------- finalize: sum all partials, write f32 scalar ----------------
__global__ __launch_bounds__(256) void finalize_kernel(const double* __restrict__ ws,
                                                       float* __restrict__ out) {
    __shared__ double sm[4];
    double v = 0.0;
    for (int i = threadIdx.x; i < TOTAL_SLOTS; i += 256) v += ws[i];
    const double tot = block_reduce(v, sm);
    if (threadIdx.x == 0) out[0] = (float)tot;
}

extern "C" void kernel_launch(void* const* d_in, const int* in_sizes, int n_in,
                              void* d_out, int out_size, void* d_ws, size_t ws_size,
                              hipStream_t stream) {
    const float* x    = (const float*)d_in[0];
    const float* kb   = (const float*)d_in[1];
    const float* b0   = (const float*)d_in[2];
    const float* kt   = (const float*)d_in[3];
    const float* t0   = (const float*)d_in[4];
    const float* ku   = (const float*)d_in[5];
    const float* s0   = (const float*)d_in[6];
    const float* kd   = (const float*)d_in[7];
    const float* nd   = (const float*)d_in[8];
    const float* d0   = (const float*)d_in[9];
    const float* kp   = (const float*)d_in[10];
    const float* p0   = (const float*)d_in[11];
    const float* eps  = (const float*)d_in[12];
    const float* rmin = (const float*)d_in[13];
    const float* kqq  = (const float*)d_in[14];
    const int* bond   = (const int*)d_in[15];
    const int* angle  = (const int*)d_in[16];
    const int* ub     = (const int*)d_in[17];
    const int* dih    = (const int*)d_in[18];
    const int* imp    = (const int*)d_in[19];
    const int* cent   = (const int*)d_in[20];

    double* ws = (double*)d_ws;

    ff_kernel<<<NB_BLOCKS, 256, 0, stream>>>(
        (const float4*)x, (const float4*)eps, (const float4*)rmin, (const float4*)kqq,
        kb, b0, kt, t0, ku, s0, kd, nd, d0, kp, p0,
        bond, angle, ub, dih, imp, cent, ws);
    finalize_kernel<<<1, 256, 0, stream>>>(ws, (float*)d_out);
}

// Round 2
// 216.447 us; speedup vs baseline: 1.0022x; 1.0022x over previous
//
#include <hip/hip_runtime.h>

#define NATOM   4096
#define NG4     (NATOM / 4)       // 1024 float4 groups per row
#define NBOND   6144
#define NANGLE  8192
#define NUB     4096
#define NDIH    12288
#define NIMP    2048

#define NB_BLOCKS   2048          // block b -> rows b and NATOM-1-b (merged stream)
#define BOND_ITEMS  (NBOND + NANGLE + NUB + NDIH + NIMP)   // 32768
#define ITEMS_PER_BLOCK (BOND_ITEMS / NB_BLOCKS)            // 16, exact
#define TOTAL_SLOTS NB_BLOCKS                               // 2048 doubles in d_ws

#define DEG2RAD 0.017453292519943295f

// keep a float4's components live-in-register at this program point:
// forces the load to be issued before here and its result held (defeats
// the compiler's register-minimizing load sinking).  [guide rule #17]
#define KEEPALIVE4(v) asm volatile("" :: "v"((v).x), "v"((v).y), "v"((v).z), "v"((v).w))

// ---- block reduction (sum of doubles), result valid on thread 0 ----
static __device__ __forceinline__ double block_reduce(double v, double* sm) {
    #pragma unroll
    for (int off = 32; off > 0; off >>= 1) v += __shfl_down(v, off, 64);
    const int lane = threadIdx.x & 63, wid = threadIdx.x >> 6;
    __syncthreads();                 // safe LDS reuse across successive calls
    if (lane == 0) sm[wid] = v;
    __syncthreads();
    double r = 0.0;
    if (threadIdx.x == 0) {
        const int nw = blockDim.x >> 6;
        for (int w = 0; w < nw; ++w) r += sm[w];
    }
    return r;
}

// one pair's vdW + electrostatic contribution (f32), predicated
static __device__ __forceinline__ float pair_term(
    float xi0, float xi1, float xi2,
    float xj0, float xj1, float xj2,
    float e, float r, float q, bool valid)
{
    const float dx = xi0 - xj0, dy = xi1 - xj1, dz = xi2 - xj2;
    float d2 = fmaf(dx, dx, fmaf(dy, dy, dz * dz));
    d2 = fmaxf(d2, 1e-12f);
    float inv = rsqrtf(d2);                       // ~1-2 ulp
    const float t = inv * inv;
    inv = inv * fmaf(-0.5f * d2, t, 1.5f);        // one Newton step -> ~0.5 ulp
    const float rod = r * inv;
    const float r2 = rod * rod;
    const float r6 = r2 * r2 * r2;
    const float v = fmaf(e * r6, r6 - 2.0f, q * inv);
    return valid ? v : 0.0f;
}

// process one float4-group of row `i` (coords of i given), f32 partial
static __device__ __forceinline__ float group_term(
    int i, float xi0, float xi1, float xi2, int g,
    float4 e, float4 r, float4 q, float4 xa, float4 xb, float4 xc)
{
    const int j0 = 4 * g;
    float s;
    s  = pair_term(xi0,xi1,xi2, xa.x,xa.y,xa.z, e.x,r.x,q.x, j0+0 > i);
    s += pair_term(xi0,xi1,xi2, xa.w,xb.x,xb.y, e.y,r.y,q.y, j0+1 > i);
    s += pair_term(xi0,xi1,xi2, xb.z,xb.w,xc.x, e.z,r.z,q.z, j0+2 > i);
    s += pair_term(xi0,xi1,xi2, xc.y,xc.z,xc.w, e.w,r.w,q.w, j0+3 > i);
    return s;
}

// ---------------- bonded terms ----------------
static __device__ __forceinline__ float torsion(const float* __restrict__ x,
                                                int i0, int i1, int i2, int i3) {
    const float ax = x[3*i1] - x[3*i0], ay = x[3*i1+1] - x[3*i0+1], az = x[3*i1+2] - x[3*i0+2];
    const float bx = x[3*i2] - x[3*i1], by = x[3*i2+1] - x[3*i1+1], bz = x[3*i2+2] - x[3*i1+2];
    const float cx = x[3*i3] - x[3*i2], cy = x[3*i3+1] - x[3*i2+1], cz = x[3*i3+2] - x[3*i2+2];
    const float n1x = ay*bz - az*by, n1y = az*bx - ax*bz, n1z = ax*by - ay*bx;
    const float n2x = by*cz - bz*cy, n2y = bz*cx - bx*cz, n2z = bx*cy - by*cx;
    const float dt  = n1x*n2x + n1y*n2y + n1z*n2z;
    const float nn1 = sqrtf(n1x*n1x + n1y*n1y + n1z*n1z);
    const float nn2 = sqrtf(n2x*n2x + n2y*n2y + n2z*n2z);
    float c = dt / (nn1 * nn2);
    c = fminf(fmaxf(c, -0.9999f), 0.9999f);
    const float ang = acosf(c);
    const float sx = n1y*n2z - n1z*n2y, sy = n1z*n2x - n1x*n2z, sz = n1x*n2y - n1y*n2x;
    const float s = sx*bx + sy*by + sz*bz;
    const float sg = (s > 0.0f) ? 1.0f : ((s < 0.0f) ? -1.0f : 0.0f);
    return ang * sg;
}

// bonded item t in [0, BOND_ITEMS): returns its energy contribution (f32)
static __device__ __forceinline__ float bonded_item(
    const float* __restrict__ x, int t,
    const float* __restrict__ kb, const float* __restrict__ b0,
    const float* __restrict__ kt, const float* __restrict__ t0,
    const float* __restrict__ ku, const float* __restrict__ s0,
    const float* __restrict__ kd, const float* __restrict__ nd, const float* __restrict__ d0,
    const float* __restrict__ kp, const float* __restrict__ p0,
    const int* __restrict__ bond, const int* __restrict__ angle,
    const int* __restrict__ ub,   const int* __restrict__ dih,
    const int* __restrict__ imp)
{
    if (t < NBOND) {
        const int m = t;
        const int i = bond[2*m], j = bond[2*m+1];
        const float dx = x[3*i]-x[3*j], dy = x[3*i+1]-x[3*j+1], dz = x[3*i+2]-x[3*j+2];
        const float dis = sqrtf(dx*dx + dy*dy + dz*dz);
        const float d = dis - b0[m];
        return kb[m] * d * d;
    } else if (t < NBOND + NANGLE) {
        const int m = t - NBOND;
        const int i = angle[3*m], j = angle[3*m+1], k = angle[3*m+2];
        const float bax = x[3*i]-x[3*j], bay = x[3*i+1]-x[3*j+1], baz = x[3*i+2]-x[3*j+2];
        const float bcx = x[3*k]-x[3*j], bcy = x[3*k+1]-x[3*j+1], bcz = x[3*k+2]-x[3*j+2];
        const float dt  = bax*bcx + bay*bcy + baz*bcz;
        const float na  = sqrtf(bax*bax + bay*bay + baz*baz);
        const float nb  = sqrtf(bcx*bcx + bcy*bcy + bcz*bcz);
        float c = dt / (na * nb);
        c = fminf(fmaxf(c, -0.9999f), 0.9999f);
        const float theta = acosf(c);
        const float d = theta - t0[m] * DEG2RAD;
        return kt[m] * d * d;
    } else if (t < NBOND + NANGLE + NUB) {
        const int m = t - NBOND - NANGLE;
        const int i = ub[2*m], j = ub[2*m+1];
        const float dx = x[3*i]-x[3*j], dy = x[3*i+1]-x[3*j+1], dz = x[3*i+2]-x[3*j+2];
        const float dis = sqrtf(dx*dx + dy*dy + dz*dz);
        const float d = dis - s0[m];
        return ku[m] * d * d;
    } else if (t < NBOND + NANGLE + NUB + NDIH) {
        const int m = t - NBOND - NANGLE - NUB;
        const float delta = torsion(x, dih[4*m], dih[4*m+1], dih[4*m+2], dih[4*m+3]);
        return kd[m] * (1.0f + cosf(nd[m] * delta - d0[m] * DEG2RAD));
    } else {
        const int m = t - NBOND - NANGLE - NUB - NDIH;
        const float psi = torsion(x, imp[4*m], imp[4*m+1], imp[4*m+2], imp[4*m+3]);
        const float d = psi - p0[m] * DEG2RAD;
        return kp[m] * d * d;
    }
}

// ---------------- fused kernel: 2048 uniform blocks ----------------
// Block b: nonbonded rows {b, 4095-b} merged into one balanced 1024/1025-slot
// stream, + 16 bonded items, + central (block 0).
// This round: pin ALL 12 matrix loads in flight per wave (KEEPALIVE4 +
// sched_barrier) to maximize memory-level parallelism; compiler previously
// serialized them into 36-VGPR chunks.
__global__ __launch_bounds__(256) void ff_kernel(
    const float4* __restrict__ xv,
    const float4* __restrict__ eps,
    const float4* __restrict__ rmin,
    const float4* __restrict__ kqq,
    const float* __restrict__ kb, const float* __restrict__ b0,
    const float* __restrict__ kt, const float* __restrict__ t0,
    const float* __restrict__ ku, const float* __restrict__ s0,
    const float* __restrict__ kd, const float* __restrict__ nd, const float* __restrict__ d0,
    const float* __restrict__ kp, const float* __restrict__ p0,
    const int* __restrict__ bond, const int* __restrict__ angle,
    const int* __restrict__ ub,   const int* __restrict__ dih,
    const int* __restrict__ imp,  const int* __restrict__ central,
    double* __restrict__ ws)
{
    __shared__ double sm[4];
    const float* __restrict__ x = (const float*)xv;
    const int b = (int)blockIdx.x;
    const int t = (int)threadIdx.x;

    // ---------------- nonbonded (merged rows) ----------------
    const int i0 = b, i1 = NATOM - 1 - b;
    const int g00 = (i0 + 1) >> 2;       // first group of row i0
    const int g01 = (i1 + 1) >> 2;       // first group of row i1
    const int c0  = NG4 - g00;           // valid slots for row i0
    const int c1  = NG4 - g01;           // valid slots for row i1
    const int S   = c0 + c1;             // 1024 or 1025

    const float a0x = x[3*i0], a0y = x[3*i0+1], a0z = x[3*i0+2];
    const float a1x = x[3*i1], a1y = x[3*i1+1], a1z = x[3*i1+2];

    // slot s in [0,1024): s < c0 -> (row i0, group g00+s); else (row i1, group g01+s-c0)
    int   gs[4], is[4], idx[4];
    float xs0[4], xs1[4], xs2[4];
    #pragma unroll
    for (int u = 0; u < 4; ++u) {
        const int s   = t + (u << 8);
        const bool in0 = s < c0;
        const int g   = in0 ? (g00 + s) : (g01 + (s - c0));
        gs[u]  = g;
        is[u]  = in0 ? i0 : i1;
        xs0[u] = in0 ? a0x : a1x;
        xs1[u] = in0 ? a0y : a1y;
        xs2[u] = in0 ? a0z : a1z;
        idx[u] = (in0 ? i0 : i1) * NG4 + g;      // < 2^22, 32-bit safe
    }

    // phase A: 12 independent coalesced matrix loads, ALL issued back-to-back
    // and held live (48 dest VGPRs).  Grouped by u so the loads consumed first
    // are the oldest in the vmem queue.
    float4 le[4], lr[4], lq[4];
    #pragma unroll
    for (int u = 0; u < 4; ++u) {
        le[u] = eps [idx[u]];
        lr[u] = rmin[idx[u]];
        lq[u] = kqq [idx[u]];
    }
    __builtin_amdgcn_sched_barrier(0);   // nothing crosses: loads stay above
    #pragma unroll
    for (int u = 0; u < 4; ++u) {
        KEEPALIVE4(le[u]); KEEPALIVE4(lr[u]); KEEPALIVE4(lq[u]);
    }

    // phase B: coords (L1/L2-hot) + math; all 1024 base slots are valid
    double acc = 0.0;
    #pragma unroll
    for (int u = 0; u < 4; ++u) {
        const int g3 = 3 * gs[u];
        const float4 xa = xv[g3], xb = xv[g3+1], xc = xv[g3+2];
        acc += (double)group_term(is[u], xs0[u], xs1[u], xs2[u], gs[u],
                                  le[u], lr[u], lq[u], xa, xb, xc);
    }

    // rare 1025th slot (S == 1025 for b%4 in {1,2}): one group on row i1
    if (S > 1024) {                       // uniform per block
        if (t == 0) {
            const int g  = g01 + (1024 - c0);
            const int id = i1 * NG4 + g;
            const float4 e = eps[id], r = rmin[id], q = kqq[id];
            const int g3 = 3 * g;
            const float4 xa = xv[g3], xb = xv[g3+1], xc = xv[g3+2];
            acc += (double)group_term(i1, a1x, a1y, a1z, g, e, r, q, xa, xb, xc);
        }
    }

    // ---------------- bonded: exactly 16 items per block ----------------
    if (t < ITEMS_PER_BLOCK) {
        const int item = b * ITEMS_PER_BLOCK + t;
        acc += (double)bonded_item(x, item, kb, b0, kt, t0, ku, s0,
                                   kd, nd, d0, kp, p0, bond, angle, ub, dih, imp);
    }

    // ---------------- central term: block 0 only ----------------
    double cext = 0.0;
    if (b == 0) {
        if (*central != 0) {              // uniform per block
            double sx = 0.0, sy = 0.0, sz = 0.0, s2 = 0.0;
            for (int i = t; i < NATOM; i += 256) {
                const float px = x[3*i], py = x[3*i+1], pz = x[3*i+2];
                sx += px; sy += py; sz += pz;
                s2 += (double)px*px + (double)py*py + (double)pz*pz;
            }
            const double rx = block_reduce(sx, sm);
            const double ry = block_reduce(sy, sm);
            const double rz = block_reduce(sz, sm);
            const double r2 = block_reduce(s2, sm);
            if (t == 0)
                cext = 0.1 * (r2 - (rx*rx + ry*ry + rz*rz) / (double)NATOM);
        }
    }

    const double tot = block_reduce(acc, sm);
    if (t == 0) ws[b] = tot + cext;
}

// ---------------- finalize: sum all partials, write f32 scalar ----------------
__global__ __launch_bounds__(256) void finalize_kernel(const double* __restrict__ ws,
                                                       float* __restrict__ out) {
    __shared__ double sm[4];
    double v = 0.0;
    for (int i = threadIdx.x; i < TOTAL_SLOTS; i += 256) v += ws[i];
    const double tot = block_reduce(v, sm);
    if (threadIdx.x == 0) out[0] = (float)tot;
}

extern "C" void kernel_launch(void* const* d_in, const int* in_sizes, int n_in,
                              void* d_out, int out_size, void* d_ws, size_t ws_size,
                              hipStream_t stream) {
    const float* x    = (const float*)d_in[0];
    const float* kb   = (const float*)d_in[1];
    const float* b0   = (const float*)d_in[2];
    const float* kt   = (const float*)d_in[3];
    const float* t0   = (const float*)d_in[4];
    const float* ku   = (const float*)d_in[5];
    const float* s0   = (const float*)d_in[6];
    const float* kd   = (const float*)d_in[7];
    const float* nd   = (const float*)d_in[8];
    const float* d0   = (const float*)d_in[9];
    const float* kp   = (const float*)d_in[10];
    const float* p0   = (const float*)d_in[11];
    const float* eps  = (const float*)d_in[12];
    const float* rmin = (const float*)d_in[13];
    const float* kqq  = (const float*)d_in[14];
    const int* bond   = (const int*)d_in[15];
    const int* angle  = (const int*)d_in[16];
    const int* ub     = (const int*)d_in[17];
    const int* dih    = (const int*)d_in[18];
    const int* imp    = (const int*)d_in[19];
    const int* cent   = (const int*)d_in[20];

    double* ws = (double*)d_ws;

    ff_kernel<<<NB_BLOCKS, 256, 0, stream>>>(
        (const float4*)x, (const float4*)eps, (const float4*)rmin, (const float4*)kqq,
        kb, b0, kt, t0, ku, s0, kd, nd, d0, kp, p0,
        bond, angle, ub, dih, imp, cent, ws);
    finalize_kernel<<<1, 256, 0, stream>>>(ws, (float*)d_out);
}

// Round 3
// 213.591 us; speedup vs baseline: 1.0156x; 1.0134x over previous
//
#include <hip/hip_runtime.h>

#define NATOM   4096
#define NG4     (NATOM / 4)       // 1024 float4 groups per row
#define NBOND   6144
#define NANGLE  8192
#define NUB     4096
#define NDIH    12288
#define NIMP    2048

#define NB_BLOCKS   2048          // block b -> rows b and NATOM-1-b (merged stream)
#define BOND_ITEMS  (NBOND + NANGLE + NUB + NDIH + NIMP)   // 32768
#define ITEMS_PER_BLOCK (BOND_ITEMS / NB_BLOCKS)            // 16, exact
#define TOTAL_SLOTS NB_BLOCKS                               // 2048 doubles in d_ws

#define DEG2RAD 0.017453292519943295f

// global -> LDS DMA, 16 B per lane. LDS dest must be wave-uniform base;
// HW writes lane l at dest + 16*l. Global src is per-lane.
#define GLOAD16(g, l)                                                     \
    __builtin_amdgcn_global_load_lds(                                     \
        (__attribute__((address_space(1))) void*)(g),                     \
        (__attribute__((address_space(3))) void*)(l), 16, 0, 0)

// ---- block reduction (sum of doubles), result valid on thread 0 ----
static __device__ __forceinline__ double block_reduce(double v, double* sm) {
    #pragma unroll
    for (int off = 32; off > 0; off >>= 1) v += __shfl_down(v, off, 64);
    const int lane = threadIdx.x & 63, wid = threadIdx.x >> 6;
    __syncthreads();                 // safe LDS reuse across successive calls
    if (lane == 0) sm[wid] = v;
    __syncthreads();
    double r = 0.0;
    if (threadIdx.x == 0) {
        const int nw = blockDim.x >> 6;
        for (int w = 0; w < nw; ++w) r += sm[w];
    }
    return r;
}

// one pair's vdW + electrostatic contribution (f32), predicated
static __device__ __forceinline__ float pair_term(
    float xi0, float xi1, float xi2,
    float xj0, float xj1, float xj2,
    float e, float r, float q, bool valid)
{
    const float dx = xi0 - xj0, dy = xi1 - xj1, dz = xi2 - xj2;
    float d2 = fmaf(dx, dx, fmaf(dy, dy, dz * dz));
    d2 = fmaxf(d2, 1e-12f);
    float inv = rsqrtf(d2);                       // ~1-2 ulp
    const float t = inv * inv;
    inv = inv * fmaf(-0.5f * d2, t, 1.5f);        // one Newton step -> ~0.5 ulp
    const float rod = r * inv;
    const float r2 = rod * rod;
    const float r6 = r2 * r2 * r2;
    const float v = fmaf(e * r6, r6 - 2.0f, q * inv);
    return valid ? v : 0.0f;
}

// process one float4-group of row `i` (coords of i given), f32 partial
static __device__ __forceinline__ float group_term(
    int i, float xi0, float xi1, float xi2, int g,
    float4 e, float4 r, float4 q, float4 xa, float4 xb, float4 xc)
{
    const int j0 = 4 * g;
    float s;
    s  = pair_term(xi0,xi1,xi2, xa.x,xa.y,xa.z, e.x,r.x,q.x, j0+0 > i);
    s += pair_term(xi0,xi1,xi2, xa.w,xb.x,xb.y, e.y,r.y,q.y, j0+1 > i);
    s += pair_term(xi0,xi1,xi2, xb.z,xb.w,xc.x, e.z,r.z,q.z, j0+2 > i);
    s += pair_term(xi0,xi1,xi2, xc.y,xc.z,xc.w, e.w,r.w,q.w, j0+3 > i);
    return s;
}

// ---------------- bonded terms ----------------
static __device__ __forceinline__ float torsion(const float* __restrict__ x,
                                                int i0, int i1, int i2, int i3) {
    const float ax = x[3*i1] - x[3*i0], ay = x[3*i1+1] - x[3*i0+1], az = x[3*i1+2] - x[3*i0+2];
    const float bx = x[3*i2] - x[3*i1], by = x[3*i2+1] - x[3*i1+1], bz = x[3*i2+2] - x[3*i1+2];
    const float cx = x[3*i3] - x[3*i2], cy = x[3*i3+1] - x[3*i2+1], cz = x[3*i3+2] - x[3*i2+2];
    const float n1x = ay*bz - az*by, n1y = az*bx - ax*bz, n1z = ax*by - ay*bx;
    const float n2x = by*cz - bz*cy, n2y = bz*cx - bx*cz, n2z = bx*cy - by*cx;
    const float dt  = n1x*n2x + n1y*n2y + n1z*n2z;
    const float nn1 = sqrtf(n1x*n1x + n1y*n1y + n1z*n1z);
    const float nn2 = sqrtf(n2x*n2x + n2y*n2y + n2z*n2z);
    float c = dt / (nn1 * nn2);
    c = fminf(fmaxf(c, -0.9999f), 0.9999f);
    const float ang = acosf(c);
    const float sx = n1y*n2z - n1z*n2y, sy = n1z*n2x - n1x*n2z, sz = n1x*n2y - n1y*n2x;
    const float s = sx*bx + sy*by + sz*bz;
    const float sg = (s > 0.0f) ? 1.0f : ((s < 0.0f) ? -1.0f : 0.0f);
    return ang * sg;
}

// bonded item t in [0, BOND_ITEMS): returns its energy contribution (f32)
static __device__ __forceinline__ float bonded_item(
    const float* __restrict__ x, int t,
    const float* __restrict__ kb, const float* __restrict__ b0,
    const float* __restrict__ kt, const float* __restrict__ t0,
    const float* __restrict__ ku, const float* __restrict__ s0,
    const float* __restrict__ kd, const float* __restrict__ nd, const float* __restrict__ d0,
    const float* __restrict__ kp, const float* __restrict__ p0,
    const int* __restrict__ bond, const int* __restrict__ angle,
    const int* __restrict__ ub,   const int* __restrict__ dih,
    const int* __restrict__ imp)
{
    if (t < NBOND) {
        const int m = t;
        const int i = bond[2*m], j = bond[2*m+1];
        const float dx = x[3*i]-x[3*j], dy = x[3*i+1]-x[3*j+1], dz = x[3*i+2]-x[3*j+2];
        const float dis = sqrtf(dx*dx + dy*dy + dz*dz);
        const float d = dis - b0[m];
        return kb[m] * d * d;
    } else if (t < NBOND + NANGLE) {
        const int m = t - NBOND;
        const int i = angle[3*m], j = angle[3*m+1], k = angle[3*m+2];
        const float bax = x[3*i]-x[3*j], bay = x[3*i+1]-x[3*j+1], baz = x[3*i+2]-x[3*j+2];
        const float bcx = x[3*k]-x[3*j], bcy = x[3*k+1]-x[3*j+1], bcz = x[3*k+2]-x[3*j+2];
        const float dt  = bax*bcx + bay*bcy + baz*bcz;
        const float na  = sqrtf(bax*bax + bay*bay + baz*baz);
        const float nb  = sqrtf(bcx*bcx + bcy*bcy + bcz*bcz);
        float c = dt / (na * nb);
        c = fminf(fmaxf(c, -0.9999f), 0.9999f);
        const float theta = acosf(c);
        const float d = theta - t0[m] * DEG2RAD;
        return kt[m] * d * d;
    } else if (t < NBOND + NANGLE + NUB) {
        const int m = t - NBOND - NANGLE;
        const int i = ub[2*m], j = ub[2*m+1];
        const float dx = x[3*i]-x[3*j], dy = x[3*i+1]-x[3*j+1], dz = x[3*i+2]-x[3*j+2];
        const float dis = sqrtf(dx*dx + dy*dy + dz*dz);
        const float d = dis - s0[m];
        return ku[m] * d * d;
    } else if (t < NBOND + NANGLE + NUB + NDIH) {
        const int m = t - NBOND - NANGLE - NUB;
        const float delta = torsion(x, dih[4*m], dih[4*m+1], dih[4*m+2], dih[4*m+3]);
        return kd[m] * (1.0f + cosf(nd[m] * delta - d0[m] * DEG2RAD));
    } else {
        const int m = t - NBOND - NANGLE - NUB - NDIH;
        const float psi = torsion(x, imp[4*m], imp[4*m+1], imp[4*m+2], imp[4*m+3]);
        const float d = psi - p0[m] * DEG2RAD;
        return kp[m] * d * d;
    }
}

// ---------------- fused kernel: 2048 blocks, LDS-DMA staged ----------------
// Block b: nonbonded rows {b, 4095-b} merged into one balanced 1024/1025-slot
// stream. The 3 matrix streams are staged global->LDS via global_load_lds
// (DMA path, no VGPR round-trip), double-buffered in 4 chunks of 256 slots,
// with counted vmcnt(3) + raw s_barrier (pipeline never drained mid-loop).
__global__ __launch_bounds__(256) void ff_kernel(
    const float4* __restrict__ xv,
    const float4* __restrict__ eps,
    const float4* __restrict__ rmin,
    const float4* __restrict__ kqq,
    const float* __restrict__ kb, const float* __restrict__ b0,
    const float* __restrict__ kt, const float* __restrict__ t0,
    const float* __restrict__ ku, const float* __restrict__ s0,
    const float* __restrict__ kd, const float* __restrict__ nd, const float* __restrict__ d0,
    const float* __restrict__ kp, const float* __restrict__ p0,
    const int* __restrict__ bond, const int* __restrict__ angle,
    const int* __restrict__ ub,   const int* __restrict__ dih,
    const int* __restrict__ imp,  const int* __restrict__ central,
    double* __restrict__ ws)
{
    __shared__ float4 bufE[2][256], bufR[2][256], bufQ[2][256];   // 24 KiB
    __shared__ double sm[4];
    const float* __restrict__ x = (const float*)xv;
    const int b = (int)blockIdx.x;
    const int t = (int)threadIdx.x;
    const int lane = t & 63, w = t >> 6;

    // ---------------- nonbonded (merged rows) ----------------
    const int i0 = b, i1 = NATOM - 1 - b;
    const int g00 = (i0 + 1) >> 2;       // first group of row i0
    const int g01 = (i1 + 1) >> 2;       // first group of row i1
    const int c0  = NG4 - g00;           // valid slots for row i0
    const int c1  = NG4 - g01;           // valid slots for row i1
    const int S   = c0 + c1;             // 1024 or 1025

    const float a0x = x[3*i0], a0y = x[3*i0+1], a0z = x[3*i0+2];
    const float a1x = x[3*i1], a1y = x[3*i1+1], a1z = x[3*i1+2];

    // stage chunk c (slots [c*256, c*256+256)) into buffer bi:
    // wave w stages its 64 slots for all 3 matrices (3 DMA instrs/wave).
    auto stage = [&](int c, int bi) {
        const int s   = (c << 8) + (w << 6) + lane;
        const bool in0 = s < c0;
        const int g   = in0 ? (g00 + s) : (g01 + (s - c0));
        const int id  = (in0 ? i0 : i1) * NG4 + g;   // per-lane global src
        float4* bE = &bufE[bi][w << 6];              // wave-uniform LDS dest
        float4* bR = &bufR[bi][w << 6];
        float4* bQ = &bufQ[bi][w << 6];
        GLOAD16(eps  + id, bE);
        GLOAD16(rmin + id, bR);
        GLOAD16(kqq  + id, bQ);
    };

    double acc = 0.0;

    stage(0, 0);                                     // prologue: 3 in flight
    #pragma unroll
    for (int c = 0; c < 4; ++c) {
        if (c < 3) {
            stage(c + 1, (c + 1) & 1);               // 6 in flight
            asm volatile("s_waitcnt vmcnt(3)" ::: "memory");  // chunk c landed
        } else {
            asm volatile("s_waitcnt vmcnt(0)" ::: "memory");
        }
        __builtin_amdgcn_s_barrier();                // all waves' chunk-c done
        __builtin_amdgcn_sched_barrier(0);           // rule #18: no hoist above

        // compute chunk c: thread t owns slot s = c*256 + t
        const int s   = (c << 8) + t;
        const bool in0 = s < c0;
        const int g   = in0 ? (g00 + s) : (g01 + (s - c0));
        const int bi  = c & 1;
        const float4 e = bufE[bi][t], r = bufR[bi][t], q = bufQ[bi][t];
        const int g3 = 3 * g;
        const float4 xa = xv[g3], xb = xv[g3+1], xc = xv[g3+2];
        acc += (double)group_term(in0 ? i0 : i1,
                                  in0 ? a0x : a1x, in0 ? a0y : a1y, in0 ? a0z : a1z,
                                  g, e, r, q, xa, xb, xc);

        __builtin_amdgcn_sched_barrier(0);           // no sink below
        __builtin_amdgcn_s_barrier();                // buf[bi] free for restage
    }

    // rare 1025th slot (S == 1025 for b%4 in {1,2}): one group on row i1
    if (S > 1024) {                       // uniform per block
        if (t == 0) {
            const int g  = g01 + (1024 - c0);
            const int id = i1 * NG4 + g;
            const float4 e = eps[id], r = rmin[id], q = kqq[id];
            const int g3 = 3 * g;
            const float4 xa = xv[g3], xb = xv[g3+1], xc = xv[g3+2];
            acc += (double)group_term(i1, a1x, a1y, a1z, g, e, r, q, xa, xb, xc);
        }
    }

    // ---------------- bonded: exactly 16 items per block ----------------
    if (t < ITEMS_PER_BLOCK) {
        const int item = b * ITEMS_PER_BLOCK + t;
        acc += (double)bonded_item(x, item, kb, b0, kt, t0, ku, s0,
                                   kd, nd, d0, kp, p0, bond, angle, ub, dih, imp);
    }

    // ---------------- central term: block 0 only ----------------
    double cext = 0.0;
    if (b == 0) {
        if (*central != 0) {              // uniform per block
            double sx = 0.0, sy = 0.0, sz = 0.0, s2 = 0.0;
            for (int i = t; i < NATOM; i += 256) {
                const float px = x[3*i], py = x[3*i+1], pz = x[3*i+2];
                sx += px; sy += py; sz += pz;
                s2 += (double)px*px + (double)py*py + (double)pz*pz;
            }
            const double rx = block_reduce(sx, sm);
            const double ry = block_reduce(sy, sm);
            const double rz = block_reduce(sz, sm);
            const double r2 = block_reduce(s2, sm);
            if (t == 0)
                cext = 0.1 * (r2 - (rx*rx + ry*ry + rz*rz) / (double)NATOM);
        }
    }

    const double tot = block_reduce(acc, sm);
    if (t == 0) ws[b] = tot + cext;
}

// ---------------- finalize: sum all partials, write f32 scalar ----------------
__global__ __launch_bounds__(256) void finalize_kernel(const double* __restrict__ ws,
                                                       float* __restrict__ out) {
    __shared__ double sm[4];
    double v = 0.0;
    for (int i = threadIdx.x; i < TOTAL_SLOTS; i += 256) v += ws[i];
    const double tot = block_reduce(v, sm);
    if (threadIdx.x == 0) out[0] = (float)tot;
}

extern "C" void kernel_launch(void* const* d_in, const int* in_sizes, int n_in,
                              void* d_out, int out_size, void* d_ws, size_t ws_size,
                              hipStream_t stream) {
    const float* x    = (const float*)d_in[0];
    const float* kb   = (const float*)d_in[1];
    const float* b0   = (const float*)d_in[2];
    const float* kt   = (const float*)d_in[3];
    const float* t0   = (const float*)d_in[4];
    const float* ku   = (const float*)d_in[5];
    const float* s0   = (const float*)d_in[6];
    const float* kd   = (const float*)d_in[7];
    const float* nd   = (const float*)d_in[8];
    const float* d0   = (const float*)d_in[9];
    const float* kp   = (const float*)d_in[10];
    const float* p0   = (const float*)d_in[11];
    const float* eps  = (const float*)d_in[12];
    const float* rmin = (const float*)d_in[13];
    const float* kqq  = (const float*)d_in[14];
    const int* bond   = (const int*)d_in[15];
    const int* angle  = (const int*)d_in[16];
    const int* ub     = (const int*)d_in[17];
    const int* dih    = (const int*)d_in[18];
    const int* imp    = (const int*)d_in[19];
    const int* cent   = (const int*)d_in[20];

    double* ws = (double*)d_ws;

    ff_kernel<<<NB_BLOCKS, 256, 0, stream>>>(
        (const float4*)x, (const float4*)eps, (const float4*)rmin, (const float4*)kqq,
        kb, b0, kt, t0, ku, s0, kd, nd, d0, kp, p0,
        bond, angle, ub, dih, imp, cent, ws);
    finalize_kernel<<<1, 256, 0, stream>>>(ws, (float*)d_out);
}

// Round 5
// 212.473 us; speedup vs baseline: 1.0209x; 1.0053x over previous
//
#include <hip/hip_runtime.h>

#define NATOM   4096
#define NG4     (NATOM / 4)       // 1024 float4 groups per row
#define NBOND   6144
#define NANGLE  8192
#define NUB     4096
#define NDIH    12288
#define NIMP    2048

#define NB_BLOCKS   2048          // block b -> rows b and NATOM-1-b (merged stream)
#define BOND_ITEMS  (NBOND + NANGLE + NUB + NDIH + NIMP)   // 32768
#define ITEMS_PER_BLOCK (BOND_ITEMS / NB_BLOCKS)            // 16, exact
#define TOTAL_SLOTS NB_BLOCKS                               // 2048 doubles in d_ws

#define DEG2RAD 0.017453292519943295f

// Clang vector type accepted by __builtin_nontemporal_load (HIP_vector_type is not)
typedef float f32x4 __attribute__((ext_vector_type(4)));

static __device__ __forceinline__ float4 ntload4(const float4* p) {
    const f32x4 v = __builtin_nontemporal_load(reinterpret_cast<const f32x4*>(p));
    return make_float4(v.x, v.y, v.z, v.w);
}

// ---- block reduction (sum of doubles), result valid on thread 0 ----
static __device__ __forceinline__ double block_reduce(double v, double* sm) {
    #pragma unroll
    for (int off = 32; off > 0; off >>= 1) v += __shfl_down(v, off, 64);
    const int lane = threadIdx.x & 63, wid = threadIdx.x >> 6;
    __syncthreads();                 // safe LDS reuse across successive calls
    if (lane == 0) sm[wid] = v;
    __syncthreads();
    double r = 0.0;
    if (threadIdx.x == 0) {
        const int nw = blockDim.x >> 6;
        for (int w = 0; w < nw; ++w) r += sm[w];
    }
    return r;
}

// one pair's vdW + electrostatic contribution (f32), predicated
static __device__ __forceinline__ float pair_term(
    float xi0, float xi1, float xi2,
    float xj0, float xj1, float xj2,
    float e, float r, float q, bool valid)
{
    const float dx = xi0 - xj0, dy = xi1 - xj1, dz = xi2 - xj2;
    float d2 = fmaf(dx, dx, fmaf(dy, dy, dz * dz));
    d2 = fmaxf(d2, 1e-12f);
    float inv = rsqrtf(d2);                       // ~1-2 ulp
    const float t = inv * inv;
    inv = inv * fmaf(-0.5f * d2, t, 1.5f);        // one Newton step -> ~0.5 ulp
    const float rod = r * inv;
    const float r2 = rod * rod;
    const float r6 = r2 * r2 * r2;
    const float v = fmaf(e * r6, r6 - 2.0f, q * inv);
    return valid ? v : 0.0f;
}

// process one float4-group of row `i` (coords of i given), f32 partial
static __device__ __forceinline__ float group_term(
    int i, float xi0, float xi1, float xi2, int g,
    float4 e, float4 r, float4 q, float4 xa, float4 xb, float4 xc)
{
    const int j0 = 4 * g;
    float s;
    s  = pair_term(xi0,xi1,xi2, xa.x,xa.y,xa.z, e.x,r.x,q.x, j0+0 > i);
    s += pair_term(xi0,xi1,xi2, xa.w,xb.x,xb.y, e.y,r.y,q.y, j0+1 > i);
    s += pair_term(xi0,xi1,xi2, xb.z,xb.w,xc.x, e.z,r.z,q.z, j0+2 > i);
    s += pair_term(xi0,xi1,xi2, xc.y,xc.z,xc.w, e.w,r.w,q.w, j0+3 > i);
    return s;
}

// ---------------- bonded terms ----------------
static __device__ __forceinline__ float torsion(const float* __restrict__ x,
                                                int i0, int i1, int i2, int i3) {
    const float ax = x[3*i1] - x[3*i0], ay = x[3*i1+1] - x[3*i0+1], az = x[3*i1+2] - x[3*i0+2];
    const float bx = x[3*i2] - x[3*i1], by = x[3*i2+1] - x[3*i1+1], bz = x[3*i2+2] - x[3*i1+2];
    const float cx = x[3*i3] - x[3*i2], cy = x[3*i3+1] - x[3*i2+1], cz = x[3*i3+2] - x[3*i2+2];
    const float n1x = ay*bz - az*by, n1y = az*bx - ax*bz, n1z = ax*by - ay*bx;
    const float n2x = by*cz - bz*cy, n2y = bz*cx - bx*cz, n2z = bx*cy - by*cx;
    const float dt  = n1x*n2x + n1y*n2y + n1z*n2z;
    const float nn1 = sqrtf(n1x*n1x + n1y*n1y + n1z*n1z);
    const float nn2 = sqrtf(n2x*n2x + n2y*n2y + n2z*n2z);
    float c = dt / (nn1 * nn2);
    c = fminf(fmaxf(c, -0.9999f), 0.9999f);
    const float ang = acosf(c);
    const float sx = n1y*n2z - n1z*n2y, sy = n1z*n2x - n1x*n2z, sz = n1x*n2y - n1y*n2x;
    const float s = sx*bx + sy*by + sz*bz;
    const float sg = (s > 0.0f) ? 1.0f : ((s < 0.0f) ? -1.0f : 0.0f);
    return ang * sg;
}

// bonded item t in [0, BOND_ITEMS): returns its energy contribution (f32)
static __device__ __forceinline__ float bonded_item(
    const float* __restrict__ x, int t,
    const float* __restrict__ kb, const float* __restrict__ b0,
    const float* __restrict__ kt, const float* __restrict__ t0,
    const float* __restrict__ ku, const float* __restrict__ s0,
    const float* __restrict__ kd, const float* __restrict__ nd, const float* __restrict__ d0,
    const float* __restrict__ kp, const float* __restrict__ p0,
    const int* __restrict__ bond, const int* __restrict__ angle,
    const int* __restrict__ ub,   const int* __restrict__ dih,
    const int* __restrict__ imp)
{
    if (t < NBOND) {
        const int m = t;
        const int i = bond[2*m], j = bond[2*m+1];
        const float dx = x[3*i]-x[3*j], dy = x[3*i+1]-x[3*j+1], dz = x[3*i+2]-x[3*j+2];
        const float dis = sqrtf(dx*dx + dy*dy + dz*dz);
        const float d = dis - b0[m];
        return kb[m] * d * d;
    } else if (t < NBOND + NANGLE) {
        const int m = t - NBOND;
        const int i = angle[3*m], j = angle[3*m+1], k = angle[3*m+2];
        const float bax = x[3*i]-x[3*j], bay = x[3*i+1]-x[3*j+1], baz = x[3*i+2]-x[3*j+2];
        const float bcx = x[3*k]-x[3*j], bcy = x[3*k+1]-x[3*j+1], bcz = x[3*k+2]-x[3*j+2];
        const float dt  = bax*bcx + bay*bcy + baz*bcz;
        const float na  = sqrtf(bax*bax + bay*bay + baz*baz);
        const float nb  = sqrtf(bcx*bcx + bcy*bcy + bcz*bcz);
        float c = dt / (na * nb);
        c = fminf(fmaxf(c, -0.9999f), 0.9999f);
        const float theta = acosf(c);
        const float d = theta - t0[m] * DEG2RAD;
        return kt[m] * d * d;
    } else if (t < NBOND + NANGLE + NUB) {
        const int m = t - NBOND - NANGLE;
        const int i = ub[2*m], j = ub[2*m+1];
        const float dx = x[3*i]-x[3*j], dy = x[3*i+1]-x[3*j+1], dz = x[3*i+2]-x[3*j+2];
        const float dis = sqrtf(dx*dx + dy*dy + dz*dz);
        const float d = dis - s0[m];
        return ku[m] * d * d;
    } else if (t < NBOND + NANGLE + NUB + NDIH) {
        const int m = t - NBOND - NANGLE - NUB;
        const float delta = torsion(x, dih[4*m], dih[4*m+1], dih[4*m+2], dih[4*m+3]);
        return kd[m] * (1.0f + cosf(nd[m] * delta - d0[m] * DEG2RAD));
    } else {
        const int m = t - NBOND - NANGLE - NUB - NDIH;
        const float psi = torsion(x, imp[4*m], imp[4*m+1], imp[4*m+2], imp[4*m+3]);
        const float d = psi - p0[m] * DEG2RAD;
        return kp[m] * d * d;
    }
}

// ---------------- fused kernel: 2048 uniform blocks ----------------
// Block b: nonbonded rows {b, 4095-b} merged into one balanced 1024/1025-slot
// stream, + 16 bonded items, + central (block 0).
// NON-TEMPORAL loads on the three single-use matrix streams (nt cache hint
// -> no/evict-first L2+L3 allocation). Coords stay cached (heavy reuse).
// Tests the "one L2 line-fill per cycle per XCD" wall:
// 8 XCD x 128 B x 2.4 GHz = 2.46 TB/s == our invariant 2.4 TB/s.
__global__ __launch_bounds__(256) void ff_kernel(
    const float4* __restrict__ xv,
    const float4* __restrict__ eps,
    const float4* __restrict__ rmin,
    const float4* __restrict__ kqq,
    const float* __restrict__ kb, const float* __restrict__ b0,
    const float* __restrict__ kt, const float* __restrict__ t0,
    const float* __restrict__ ku, const float* __restrict__ s0,
    const float* __restrict__ kd, const float* __restrict__ nd, const float* __restrict__ d0,
    const float* __restrict__ kp, const float* __restrict__ p0,
    const int* __restrict__ bond, const int* __restrict__ angle,
    const int* __restrict__ ub,   const int* __restrict__ dih,
    const int* __restrict__ imp,  const int* __restrict__ central,
    double* __restrict__ ws)
{
    __shared__ double sm[4];
    const float* __restrict__ x = (const float*)xv;
    const int b = (int)blockIdx.x;
    const int t = (int)threadIdx.x;

    // ---------------- nonbonded (merged rows) ----------------
    const int i0 = b, i1 = NATOM - 1 - b;
    const int g00 = (i0 + 1) >> 2;       // first group of row i0
    const int g01 = (i1 + 1) >> 2;       // first group of row i1
    const int c0  = NG4 - g00;           // valid slots for row i0
    const int c1  = NG4 - g01;           // valid slots for row i1
    const int S   = c0 + c1;             // 1024 or 1025

    const float a0x = x[3*i0], a0y = x[3*i0+1], a0z = x[3*i0+2];
    const float a1x = x[3*i1], a1y = x[3*i1+1], a1z = x[3*i1+2];

    // slot s in [0,1024): s < c0 -> (row i0, group g00+s); else (row i1, group g01+s-c0)
    int   gs[4], is[4], idx[4];
    float xs0[4], xs1[4], xs2[4];
    #pragma unroll
    for (int u = 0; u < 4; ++u) {
        const int s   = t + (u << 8);
        const bool in0 = s < c0;
        const int g   = in0 ? (g00 + s) : (g01 + (s - c0));
        gs[u]  = g;
        is[u]  = in0 ? i0 : i1;
        xs0[u] = in0 ? a0x : a1x;
        xs1[u] = in0 ? a0y : a1y;
        xs2[u] = in0 ? a0z : a1z;
        idx[u] = (in0 ? i0 : i1) * NG4 + g;      // < 2^22, 32-bit safe
    }

    // phase A: 12 independent coalesced NON-TEMPORAL matrix loads
    float4 le[4], lr[4], lq[4];
    #pragma unroll
    for (int u = 0; u < 4; ++u) {
        le[u] = ntload4(eps  + idx[u]);
        lr[u] = ntload4(rmin + idx[u]);
        lq[u] = ntload4(kqq  + idx[u]);
    }

    // phase B: coords (cached, L1/L2-hot) + math; all 1024 base slots valid
    double acc = 0.0;
    #pragma unroll
    for (int u = 0; u < 4; ++u) {
        const int g3 = 3 * gs[u];
        const float4 xa = xv[g3], xb = xv[g3+1], xc = xv[g3+2];
        acc += (double)group_term(is[u], xs0[u], xs1[u], xs2[u], gs[u],
                                  le[u], lr[u], lq[u], xa, xb, xc);
    }

    // rare 1025th slot (S == 1025 for b%4 in {1,2}): one group on row i1
    if (S > 1024) {                       // uniform per block
        if (t == 0) {
            const int g  = g01 + (1024 - c0);
            const int id = i1 * NG4 + g;
            const float4 e = ntload4(eps  + id);
            const float4 r = ntload4(rmin + id);
            const float4 q = ntload4(kqq  + id);
            const int g3 = 3 * g;
            const float4 xa = xv[g3], xb = xv[g3+1], xc = xv[g3+2];
            acc += (double)group_term(i1, a1x, a1y, a1z, g, e, r, q, xa, xb, xc);
        }
    }

    // ---------------- bonded: exactly 16 items per block ----------------
    if (t < ITEMS_PER_BLOCK) {
        const int item = b * ITEMS_PER_BLOCK + t;
        acc += (double)bonded_item(x, item, kb, b0, kt, t0, ku, s0,
                                   kd, nd, d0, kp, p0, bond, angle, ub, dih, imp);
    }

    // ---------------- central term: block 0 only ----------------
    double cext = 0.0;
    if (b == 0) {
        if (*central != 0) {              // uniform per block
            double sx = 0.0, sy = 0.0, sz = 0.0, s2 = 0.0;
            for (int i = t; i < NATOM; i += 256) {
                const float px = x[3*i], py = x[3*i+1], pz = x[3*i+2];
                sx += px; sy += py; sz += pz;
                s2 += (double)px*px + (double)py*py + (double)pz*pz;
            }
            const double rx = block_reduce(sx, sm);
            const double ry = block_reduce(sy, sm);
            const double rz = block_reduce(sz, sm);
            const double r2 = block_reduce(s2, sm);
            if (t == 0)
                cext = 0.1 * (r2 - (rx*rx + ry*ry + rz*rz) / (double)NATOM);
        }
    }

    const double tot = block_reduce(acc, sm);
    if (t == 0) ws[b] = tot + cext;
}

// ---------------- finalize: sum all partials, write f32 scalar ----------------
__global__ __launch_bounds__(256) void finalize_kernel(const double* __restrict__ ws,
                                                       float* __restrict__ out) {
    __shared__ double sm[4];
    double v = 0.0;
    for (int i = threadIdx.x; i < TOTAL_SLOTS; i += 256) v += ws[i];
    const double tot = block_reduce(v, sm);
    if (threadIdx.x == 0) out[0] = (float)tot;
}

extern "C" void kernel_launch(void* const* d_in, const int* in_sizes, int n_in,
                              void* d_out, int out_size, void* d_ws, size_t ws_size,
                              hipStream_t stream) {
    const float* x    = (const float*)d_in[0];
    const float* kb   = (const float*)d_in[1];
    const float* b0   = (const float*)d_in[2];
    const float* kt   = (const float*)d_in[3];
    const float* t0   = (const float*)d_in[4];
    const float* ku   = (const float*)d_in[5];
    const float* s0   = (const float*)d_in[6];
    const float* kd   = (const float*)d_in[7];
    const float* nd   = (const float*)d_in[8];
    const float* d0   = (const float*)d_in[9];
    const float* kp   = (const float*)d_in[10];
    const float* p0   = (const float*)d_in[11];
    const float* eps  = (const float*)d_in[12];
    const float* rmin = (const float*)d_in[13];
    const float* kqq  = (const float*)d_in[14];
    const int* bond   = (const int*)d_in[15];
    const int* angle  = (const int*)d_in[16];
    const int* ub     = (const int*)d_in[17];
    const int* dih    = (const int*)d_in[18];
    const int* imp    = (const int*)d_in[19];
    const int* cent   = (const int*)d_in[20];

    double* ws = (double*)d_ws;

    ff_kernel<<<NB_BLOCKS, 256, 0, stream>>>(
        (const float4*)x, (const float4*)eps, (const float4*)rmin, (const float4*)kqq,
        kb, b0, kt, t0, ku, s0, kd, nd, d0, kp, p0,
        bond, angle, ub, dih, imp, cent, ws);
    finalize_kernel<<<1, 256, 0, stream>>>(ws, (float*)d_out);
}